// Round 2
// baseline (2047.618 us; speedup 1.0000x reference)
//
#include <hip/hip_runtime.h>
#include <hip/hip_bf16.h>

// Problem constants (match reference)
#define NN 100000
#define NE 3200000
#define F_IN 512
#define NHID 64
#define NCLS 40

// CSR build: 2048 buckets of 49 rows each (2048*49 = 100352 >= NN)
#define NB 2048
#define RPB 49
#define BCAP 2048  // LDS staging capacity per bucket (mean 1562, +12 sigma safe)

// ---------------------------------------------------------------------------
// GEMM1: H[N,64] = relu(F[N,512] @ W1[512,64] + b1)
// ---------------------------------------------------------------------------
__global__ __launch_bounds__(256) void gemm1_kernel(
    const float* __restrict__ F, const float* __restrict__ W1,
    const float* __restrict__ b1, float* __restrict__ H) {
  __shared__ float As[16][68];
  __shared__ float Bs[16][64];
  const int tid = threadIdx.x;
  const int m0 = blockIdx.x * 64;
  const int ty = tid >> 4;
  const int tx = tid & 15;
  const int lrowA = tid >> 2;
  const int lkA = (tid & 3) * 4;
  const int lkB = tid >> 4;
  const int lcolB = (tid & 15) * 4;
  const bool rowok = (m0 + lrowA) < NN;
  const int rclamp = rowok ? (m0 + lrowA) : (NN - 1);
  const float* Fb = F + (long)rclamp * F_IN + lkA;

  float acc[4][4] = {};
  for (int k0 = 0; k0 < F_IN; k0 += 16) {
    float4 fa = *(const float4*)(Fb + k0);
    if (!rowok) fa = make_float4(0.f, 0.f, 0.f, 0.f);
    float4 wb = *(const float4*)(W1 + (long)(k0 + lkB) * NHID + lcolB);
    __syncthreads();
    As[lkA + 0][lrowA] = fa.x;
    As[lkA + 1][lrowA] = fa.y;
    As[lkA + 2][lrowA] = fa.z;
    As[lkA + 3][lrowA] = fa.w;
    *(float4*)&Bs[lkB][lcolB] = wb;
    __syncthreads();
#pragma unroll
    for (int kk = 0; kk < 16; ++kk) {
      float4 a = *(const float4*)&As[kk][ty * 4];
      float4 b = *(const float4*)&Bs[kk][tx * 4];
      float av[4] = {a.x, a.y, a.z, a.w};
      float bv[4] = {b.x, b.y, b.z, b.w};
#pragma unroll
      for (int i = 0; i < 4; ++i)
#pragma unroll
        for (int j = 0; j < 4; ++j) acc[i][j] = fmaf(av[i], bv[j], acc[i][j]);
    }
  }
  float4 bb = *(const float4*)(b1 + tx * 4);
  float bv[4] = {bb.x, bb.y, bb.z, bb.w};
#pragma unroll
  for (int i = 0; i < 4; ++i) {
    int r = m0 + ty * 4 + i;
    if (r < NN) {
      float4 o;
      o.x = fmaxf(acc[i][0] + bv[0], 0.f);
      o.y = fmaxf(acc[i][1] + bv[1], 0.f);
      o.z = fmaxf(acc[i][2] + bv[2], 0.f);
      o.w = fmaxf(acc[i][3] + bv[3], 0.f);
      *(float4*)(H + (long)r * NHID + tx * 4) = o;
    }
  }
}

// ---------------------------------------------------------------------------
// GEMM2: X0[N,40] = H[N,64] @ W2[64,40] + b2   (thread per node)
// ---------------------------------------------------------------------------
__global__ __launch_bounds__(256) void gemm2_kernel(
    const float* __restrict__ H, const float* __restrict__ W2,
    const float* __restrict__ b2, float* __restrict__ X0) {
  __shared__ float Ws[NHID * NCLS];
  __shared__ float bs[NCLS];
  const int tid = threadIdx.x;
  for (int i = tid; i < NHID * NCLS; i += 256) Ws[i] = W2[i];
  if (tid < NCLS) bs[tid] = b2[tid];
  __syncthreads();
  const int node = blockIdx.x * 256 + tid;
  if (node >= NN) return;
  float acc[NCLS];
#pragma unroll
  for (int j = 0; j < NCLS; ++j) acc[j] = bs[j];
  const float4* h4 = (const float4*)(H + (long)node * NHID);
#pragma unroll
  for (int kq = 0; kq < 16; ++kq) {
    float4 h = h4[kq];
    float hv[4] = {h.x, h.y, h.z, h.w};
#pragma unroll
    for (int u = 0; u < 4; ++u) {
      const int k = kq * 4 + u;
#pragma unroll
      for (int j = 0; j < NCLS; ++j)
        acc[j] = fmaf(hv[u], Ws[k * NCLS + j], acc[j]);
    }
  }
  float* o = X0 + (long)node * NCLS;
#pragma unroll
  for (int q = 0; q < 10; ++q) {
    float4 v = make_float4(acc[q * 4], acc[q * 4 + 1], acc[q * 4 + 2], acc[q * 4 + 3]);
    *(float4*)(o + q * 4) = v;
  }
}

// ---------------------------------------------------------------------------
// CSR build, two-level bucketed (rebuilt every call; ws is re-poisoned)
// ---------------------------------------------------------------------------
// k1: bucket histogram via LDS, 256 blocks grid-stride
__global__ __launch_bounds__(256) void bucket_hist(const int* __restrict__ row,
                                                   int* __restrict__ bcnt) {
  __shared__ int h[NB];
  const int tid = threadIdx.x;
  for (int i = tid; i < NB; i += 256) h[i] = 0;
  __syncthreads();
  for (int e = blockIdx.x * 256 + tid; e < NE; e += gridDim.x * 256)
    atomicAdd(&h[row[e] / RPB], 1);
  __syncthreads();
  for (int i = tid; i < NB; i += 256)
    if (h[i]) atomicAdd(&bcnt[i], h[i]);
}

// k2: scan bucket counts -> bbase (exclusive, NB+1), zero bcur. 1 block.
__global__ __launch_bounds__(1024) void bucket_scan(const int* __restrict__ bcnt,
                                                    int* __restrict__ bbase,
                                                    int* __restrict__ bcur) {
  __shared__ int sm[1024];
  const int t = threadIdx.x;
  int a = bcnt[2 * t], b = bcnt[2 * t + 1];
  int s = a + b;
  sm[t] = s;
  __syncthreads();
  for (int off = 1; off < 1024; off <<= 1) {
    int v = (t >= off) ? sm[t - off] : 0;
    __syncthreads();
    sm[t] += v;
    __syncthreads();
  }
  int excl = sm[t] - s;
  bbase[2 * t] = excl;
  bbase[2 * t + 1] = excl + a;
  bcur[2 * t] = 0;
  bcur[2 * t + 1] = 0;
  if (t == 1023) bbase[NB] = sm[1023];
}

// k3: scatter edges into bucket staging. Writes go to 2048 sequential
// frontiers -> lines fill while L2-resident -> ~26 MB HBM writes, not 200.
// staged.x = (col<<6)|row_local  (col<2^17, row_local<49)   staged.y = ev bits
__global__ __launch_bounds__(256) void bucket_scatter(
    const int* __restrict__ row, const int* __restrict__ col,
    const float* __restrict__ ev, const int* __restrict__ bbase,
    int* __restrict__ bcur, int2* __restrict__ staged) {
  int e = blockIdx.x * 256 + threadIdx.x;
  if (e >= NE) return;
  int r = row[e];
  int b = r / RPB;
  unsigned meta = ((unsigned)col[e] << 6) | (unsigned)(r - b * RPB);
  int pos = bbase[b] + atomicAdd(&bcur[b], 1);
  staged[pos] = make_int2((int)meta, __float_as_int(ev[e]));
}

// k4a: per-bucket degree histogram -> deg[] written coalesced
__global__ __launch_bounds__(256) void deg_hist(const int* __restrict__ bbase,
                                                const int2* __restrict__ staged,
                                                int* __restrict__ deg) {
  __shared__ int h[64];
  const int b = blockIdx.x;
  const int tid = threadIdx.x;
  const int s0 = bbase[b];
  const int cnt = bbase[b + 1] - s0;
  if (tid < 64) h[tid] = 0;
  __syncthreads();
  for (int j = tid; j < cnt; j += 256) atomicAdd(&h[staged[s0 + j].x & 63], 1);
  __syncthreads();
  int r = b * RPB + tid;
  if (tid < RPB && r < NN) deg[r] = h[tid];
}

// global scan deg -> rp (1 block)
__global__ __launch_bounds__(1024) void scan_kernel(const int* __restrict__ deg,
                                                    int* __restrict__ rp) {
  __shared__ int sm[1024];
  const int t = threadIdx.x;
  const int CH = (NN + 1023) / 1024;
  const int i0 = t * CH;
  const int i1 = (i0 + CH < NN) ? (i0 + CH) : NN;
  int s = 0;
  for (int i = i0; i < i1; ++i) s += deg[i];
  sm[t] = s;
  __syncthreads();
  for (int off = 1; off < 1024; off <<= 1) {
    int v = (t >= off) ? sm[t - off] : 0;
    __syncthreads();
    sm[t] += v;
    __syncthreads();
  }
  int run = sm[t] - s;
  for (int i = i0; i < i1; ++i) {
    rp[i] = run;
    run += deg[i];
  }
  if (t == 1023) rp[NN] = sm[1023];
}

// k4c: order each bucket's edges in LDS, stream to CSR coalesced.
__global__ __launch_bounds__(256) void bucket_emit(
    const int* __restrict__ bbase, const int2* __restrict__ staged,
    const int* __restrict__ rp, int2* __restrict__ edges) {
  __shared__ int h[64], lscan[64], lcur[64];
  __shared__ int2 pay[BCAP];
  const int b = blockIdx.x;
  const int tid = threadIdx.x;
  const int s0 = bbase[b];
  const int cnt = bbase[b + 1] - s0;
  if (cnt == 0) return;
  if (tid < 64) { h[tid] = 0; lcur[tid] = 0; }
  __syncthreads();
  for (int j = tid; j < cnt; j += 256) atomicAdd(&h[staged[s0 + j].x & 63], 1);
  __syncthreads();
  if (tid == 0) {
    int run = 0;
    for (int i = 0; i < RPB; ++i) { lscan[i] = run; run += h[i]; }
  }
  __syncthreads();
  const int g0 = rp[b * RPB];
  if (cnt <= BCAP) {
    for (int j = tid; j < cnt; j += 256) {
      int2 ed = staged[s0 + j];
      int rl = ed.x & 63;
      int p = lscan[rl] + atomicAdd(&lcur[rl], 1);
      pay[p] = make_int2((int)((unsigned)ed.x >> 6), ed.y);
    }
    __syncthreads();
    for (int j = tid; j < cnt; j += 256) edges[g0 + j] = pay[j];
  } else {  // overflow fallback (statistically unreachable): direct, L2-local
    for (int j = tid; j < cnt; j += 256) {
      int2 ed = staged[s0 + j];
      int rl = ed.x & 63;
      int p = g0 + lscan[rl] + atomicAdd(&lcur[rl], 1);
      edges[p] = make_int2((int)((unsigned)ed.x >> 6), ed.y);
    }
  }
}

// ---------------------------------------------------------------------------
// Propagation: x_out = 0.9 * (A x_in) + 0.1 * h.  10 threads per node.
// ---------------------------------------------------------------------------
__global__ __launch_bounds__(256) void prop_kernel(
    const float4* __restrict__ xin, float4* __restrict__ xout,
    const float4* __restrict__ h, const int2* __restrict__ edges,
    const int* __restrict__ rp) {
  const int t = blockIdx.x * 256 + threadIdx.x;
  const int node = t / 10;
  if (node >= NN) return;
  const int g = t - node * 10;
  const int e0 = rp[node], e1 = rp[node + 1];
  float4 acc = make_float4(0.f, 0.f, 0.f, 0.f);
  for (int e = e0; e < e1; ++e) {
    int2 ed = edges[e];
    float v = __int_as_float(ed.y);
    float4 x = xin[(long)ed.x * 10 + g];
    acc.x = fmaf(v, x.x, acc.x);
    acc.y = fmaf(v, x.y, acc.y);
    acc.z = fmaf(v, x.z, acc.z);
    acc.w = fmaf(v, x.w, acc.w);
  }
  float4 hh = h[(long)node * 10 + g];
  float4 o;
  o.x = fmaf(0.9f, acc.x, 0.1f * hh.x);
  o.y = fmaf(0.9f, acc.y, 0.1f * hh.y);
  o.z = fmaf(0.9f, acc.z, 0.1f * hh.z);
  o.w = fmaf(0.9f, acc.w, 0.1f * hh.w);
  xout[(long)node * 10 + g] = o;
}

// ---------------------------------------------------------------------------
// log_softmax over 40 classes, one thread per node
// ---------------------------------------------------------------------------
__global__ __launch_bounds__(256) void logsm_kernel(const float* __restrict__ X,
                                                    float* __restrict__ out) {
  const int node = blockIdx.x * 256 + threadIdx.x;
  if (node >= NN) return;
  const float4* x4 = (const float4*)(X + (long)node * NCLS);
  float v[NCLS];
#pragma unroll
  for (int q = 0; q < 10; ++q) {
    float4 a = x4[q];
    v[q * 4] = a.x; v[q * 4 + 1] = a.y; v[q * 4 + 2] = a.z; v[q * 4 + 3] = a.w;
  }
  float m = v[0];
#pragma unroll
  for (int j = 1; j < NCLS; ++j) m = fmaxf(m, v[j]);
  float s = 0.f;
#pragma unroll
  for (int j = 0; j < NCLS; ++j) s += expf(v[j] - m);
  const float l = m + logf(s);
  float4* o4 = (float4*)(out + (long)node * NCLS);
#pragma unroll
  for (int q = 0; q < 10; ++q) {
    float4 a = make_float4(v[q * 4] - l, v[q * 4 + 1] - l, v[q * 4 + 2] - l,
                           v[q * 4 + 3] - l);
    o4[q] = a;
  }
}

// ---------------------------------------------------------------------------
// Launch
// ---------------------------------------------------------------------------
extern "C" void kernel_launch(void* const* d_in, const int* in_sizes, int n_in,
                              void* d_out, int out_size, void* d_ws,
                              size_t ws_size, hipStream_t stream) {
  const float* F = (const float*)d_in[0];
  const int* EI = (const int*)d_in[1];
  const float* EV = (const float*)d_in[2];
  const float* W1 = (const float*)d_in[3];
  const float* b1 = (const float*)d_in[4];
  const float* W2 = (const float*)d_in[5];
  const float* b2 = (const float*)d_in[6];
  float* out = (float*)d_out;
  char* ws = (char*)d_ws;

  // ws layout with phase-based aliasing:
  // Phase A (CSR build):  STAGED [0, 25.6M)   EDG [48M, 73.6M)   aux @73.6M+
  // Phase B (gemms):      H [16M, 41.6M)  (STAGED dead)
  // Phase C (prop):       X0 [0,16M)  XA [16M,32M)  XB [32M,48M)  (H dead)
  int2* STAGED = (int2*)(ws + 0);
  float* X0 = (float*)(ws + 0);
  float* XA = (float*)(ws + 16000000);
  float* H = (float*)(ws + 16000000);
  float* XB = (float*)(ws + 32000000);
  int2* EDG = (int2*)(ws + 48000000);
  int* RP = (int*)(ws + 73600000);     // (NN+1) ints
  int* DEG = (int*)(ws + 74000256);    // NN ints
  int* BCNT = (int*)(ws + 74400512);   // NB ints
  int* BBASE = (int*)(ws + 74408704);  // NB+1 ints
  int* BCUR = (int*)(ws + 74417152);   // NB ints; end ~74,425,344

  const int* ROW = EI;       // edge_index[0]
  const int* COL = EI + NE;  // edge_index[1]

  // --- CSR build ---
  hipMemsetAsync(BCNT, 0, NB * sizeof(int), stream);
  bucket_hist<<<256, 256, 0, stream>>>(ROW, BCNT);
  bucket_scan<<<1, 1024, 0, stream>>>(BCNT, BBASE, BCUR);
  bucket_scatter<<<(NE + 255) / 256, 256, 0, stream>>>(ROW, COL, EV, BBASE,
                                                       BCUR, STAGED);
  deg_hist<<<NB, 256, 0, stream>>>(BBASE, STAGED, DEG);
  scan_kernel<<<1, 1024, 0, stream>>>(DEG, RP);
  bucket_emit<<<NB, 256, 0, stream>>>(BBASE, STAGED, RP, EDG);

  // --- MLP ---
  gemm1_kernel<<<(NN + 63) / 64, 256, 0, stream>>>(F, W1, b1, H);
  gemm2_kernel<<<(NN + 255) / 256, 256, 0, stream>>>(H, W2, b2, X0);

  // --- propagation ---
  const int tgrid = (NN * 10 + 255) / 256;
  const float* cur_in = X0;
  float* bufs[2] = {XA, XB};
  for (int it = 0; it < 10; ++it) {
    float* o = bufs[it & 1];
    prop_kernel<<<tgrid, 256, 0, stream>>>((const float4*)cur_in, (float4*)o,
                                           (const float4*)X0, EDG, RP);
    cur_in = o;
  }
  logsm_kernel<<<(NN + 255) / 256, 256, 0, stream>>>(cur_in, out);
}

// Round 3
// 1716.872 us; speedup vs baseline: 1.1926x; 1.1926x over previous
//
#include <hip/hip_runtime.h>
#include <hip/hip_bf16.h>

// Problem constants (match reference)
#define NN 100000
#define NE 3200000
#define F_IN 512
#define NHID 64
#define NCLS 40

// Radix-partition CSR build params
#define NB2 512   // row buckets
#define RPB2 196  // rows per bucket (512*196 = 100352 >= NN)
#define CHK 4096  // edges per chunk
#define NCH 782   // ceil(NE/CHK)
#define EPT 16    // edges per thread in P3 (CHK/256)
#define ECAP 7168 // emit LDS capacity (mean 6250, sigma 79 -> +11.6 sigma)

// ---------------------------------------------------------------------------
// GEMM1: H[N,64] = relu(F[N,512] @ W1[512,64] + b1)
// ---------------------------------------------------------------------------
__global__ __launch_bounds__(256) void gemm1_kernel(
    const float* __restrict__ F, const float* __restrict__ W1,
    const float* __restrict__ b1, float* __restrict__ H) {
  __shared__ float As[16][68];
  __shared__ float Bs[16][64];
  const int tid = threadIdx.x;
  const int m0 = blockIdx.x * 64;
  const int ty = tid >> 4;
  const int tx = tid & 15;
  const int lrowA = tid >> 2;
  const int lkA = (tid & 3) * 4;
  const int lkB = tid >> 4;
  const int lcolB = (tid & 15) * 4;
  const bool rowok = (m0 + lrowA) < NN;
  const int rclamp = rowok ? (m0 + lrowA) : (NN - 1);
  const float* Fb = F + (long)rclamp * F_IN + lkA;

  float acc[4][4] = {};
  for (int k0 = 0; k0 < F_IN; k0 += 16) {
    float4 fa = *(const float4*)(Fb + k0);
    if (!rowok) fa = make_float4(0.f, 0.f, 0.f, 0.f);
    float4 wb = *(const float4*)(W1 + (long)(k0 + lkB) * NHID + lcolB);
    __syncthreads();
    As[lkA + 0][lrowA] = fa.x;
    As[lkA + 1][lrowA] = fa.y;
    As[lkA + 2][lrowA] = fa.z;
    As[lkA + 3][lrowA] = fa.w;
    *(float4*)&Bs[lkB][lcolB] = wb;
    __syncthreads();
#pragma unroll
    for (int kk = 0; kk < 16; ++kk) {
      float4 a = *(const float4*)&As[kk][ty * 4];
      float4 b = *(const float4*)&Bs[kk][tx * 4];
      float av[4] = {a.x, a.y, a.z, a.w};
      float bv[4] = {b.x, b.y, b.z, b.w};
#pragma unroll
      for (int i = 0; i < 4; ++i)
#pragma unroll
        for (int j = 0; j < 4; ++j) acc[i][j] = fmaf(av[i], bv[j], acc[i][j]);
    }
  }
  float4 bb = *(const float4*)(b1 + tx * 4);
  float bv[4] = {bb.x, bb.y, bb.z, bb.w};
#pragma unroll
  for (int i = 0; i < 4; ++i) {
    int r = m0 + ty * 4 + i;
    if (r < NN) {
      float4 o;
      o.x = fmaxf(acc[i][0] + bv[0], 0.f);
      o.y = fmaxf(acc[i][1] + bv[1], 0.f);
      o.z = fmaxf(acc[i][2] + bv[2], 0.f);
      o.w = fmaxf(acc[i][3] + bv[3], 0.f);
      *(float4*)(H + (long)r * NHID + tx * 4) = o;
    }
  }
}

// ---------------------------------------------------------------------------
// GEMM2: X0[N,40] = H[N,64] @ W2[64,40] + b2   (thread per node)
// ---------------------------------------------------------------------------
__global__ __launch_bounds__(256) void gemm2_kernel(
    const float* __restrict__ H, const float* __restrict__ W2,
    const float* __restrict__ b2, float* __restrict__ X0) {
  __shared__ float Ws[NHID * NCLS];
  __shared__ float bs[NCLS];
  const int tid = threadIdx.x;
  for (int i = tid; i < NHID * NCLS; i += 256) Ws[i] = W2[i];
  if (tid < NCLS) bs[tid] = b2[tid];
  __syncthreads();
  const int node = blockIdx.x * 256 + tid;
  if (node >= NN) return;
  float acc[NCLS];
#pragma unroll
  for (int j = 0; j < NCLS; ++j) acc[j] = bs[j];
  const float4* h4 = (const float4*)(H + (long)node * NHID);
#pragma unroll
  for (int kq = 0; kq < 16; ++kq) {
    float4 h = h4[kq];
    float hv[4] = {h.x, h.y, h.z, h.w};
#pragma unroll
    for (int u = 0; u < 4; ++u) {
      const int k = kq * 4 + u;
#pragma unroll
      for (int j = 0; j < NCLS; ++j)
        acc[j] = fmaf(hv[u], Ws[k * NCLS + j], acc[j]);
    }
  }
  float* o = X0 + (long)node * NCLS;
#pragma unroll
  for (int q = 0; q < 10; ++q) {
    float4 v = make_float4(acc[q * 4], acc[q * 4 + 1], acc[q * 4 + 2], acc[q * 4 + 3]);
    *(float4*)(o + q * 4) = v;
  }
}

// ---------------------------------------------------------------------------
// P1: per-chunk bucket histogram (LDS atomics, coalesced dump)
// ---------------------------------------------------------------------------
__global__ __launch_bounds__(256) void p1_count(const int* __restrict__ row,
                                                int* __restrict__ hist) {
  __shared__ int h[NB2];
  const int tid = threadIdx.x, blk = blockIdx.x;
  for (int i = tid; i < NB2; i += 256) h[i] = 0;
  __syncthreads();
  const int e0 = blk * CHK;
#pragma unroll
  for (int k = 0; k < EPT; ++k) {
    int e = e0 + k * 256 + tid;
    if (e < NE) atomicAdd(&h[row[e] / RPB2], 1);
  }
  __syncthreads();
  for (int i = tid; i < NB2; i += 256) hist[blk * NB2 + i] = h[i];
}

// ---------------------------------------------------------------------------
// P2: exclusive scan over flat order f = b*NCH + blk (reads hist[blk][b])
// ---------------------------------------------------------------------------
__global__ __launch_bounds__(1024) void p2_scan(const int* __restrict__ hist,
                                                int* __restrict__ base) {
  __shared__ int sm[1024];
  const int t = threadIdx.x;
  const int TOT = NB2 * NCH;
  const int CH = (TOT + 1023) / 1024;
  const int f0 = t * CH;
  const int f1 = (f0 + CH < TOT) ? (f0 + CH) : TOT;
  int b = f0 / NCH, blk = f0 - b * NCH;
  int s = 0;
  for (int f = f0; f < f1; ++f) {
    s += hist[blk * NB2 + b];
    if (++blk == NCH) { blk = 0; ++b; }
  }
  sm[t] = s;
  __syncthreads();
  for (int off = 1; off < 1024; off <<= 1) {
    int v = (t >= off) ? sm[t - off] : 0;
    __syncthreads();
    sm[t] += v;
    __syncthreads();
  }
  int run = sm[t] - s;
  b = f0 / NCH;
  blk = f0 - b * NCH;
  for (int f = f0; f < f1; ++f) {
    base[f] = run;
    run += hist[blk * NB2 + b];
    if (++blk == NCH) { blk = 0; ++b; }
  }
}

// ---------------------------------------------------------------------------
// P3: partition into 512 buckets. All reordering in LDS; global writes are
// block-private contiguous runs (single-workgroup line ownership).
// staged.x = (col<<8) | row_local (col<2^17, rl<196);  staged.y = ev bits
// ---------------------------------------------------------------------------
__global__ __launch_bounds__(256) void p3_scatter(
    const int* __restrict__ row, const int* __restrict__ col,
    const float* __restrict__ ev, const int* __restrict__ base,
    int2* __restrict__ staged) {
  __shared__ int h[NB2], lscan[NB2], lcur[NB2], gbase[NB2];
  __shared__ int tmp[256];
  __shared__ int2 pay[CHK];
  __shared__ unsigned short binof[CHK];
  const int tid = threadIdx.x, blk = blockIdx.x;
  for (int i = tid; i < NB2; i += 256) { h[i] = 0; lcur[i] = 0; }
  __syncthreads();
  const int e0 = blk * CHK;
  const int n = (NE - e0 < CHK) ? (NE - e0) : CHK;
  int eb[EPT], em[EPT], ee[EPT];
#pragma unroll
  for (int k = 0; k < EPT; ++k) {
    int e = e0 + k * 256 + tid;
    if (e < NE) {
      int r = row[e];
      int b = r / RPB2;
      eb[k] = b;
      em[k] = (col[e] << 8) | (r - b * RPB2);
      ee[k] = __float_as_int(ev[e]);
      atomicAdd(&h[b], 1);
    } else {
      eb[k] = -1;
    }
  }
  __syncthreads();
  // exclusive scan over 512 bins: pair-sum + Hillis-Steele over 256
  int a = h[2 * tid], c = h[2 * tid + 1];
  tmp[tid] = a + c;
  __syncthreads();
  for (int off = 1; off < 256; off <<= 1) {
    int v = (tid >= off) ? tmp[tid - off] : 0;
    __syncthreads();
    tmp[tid] += v;
    __syncthreads();
  }
  int excl = tmp[tid] - (a + c);
  lscan[2 * tid] = excl;
  lscan[2 * tid + 1] = excl + a;
  gbase[2 * tid] = base[(2 * tid) * NCH + blk];
  gbase[2 * tid + 1] = base[(2 * tid + 1) * NCH + blk];
  __syncthreads();
#pragma unroll
  for (int k = 0; k < EPT; ++k) {
    if (eb[k] >= 0) {
      int b = eb[k];
      int p = lscan[b] + atomicAdd(&lcur[b], 1);
      pay[p] = make_int2(em[k], ee[k]);
      binof[p] = (unsigned short)b;
    }
  }
  __syncthreads();
  for (int j = tid; j < n; j += 256) {
    int b = binof[j];
    staged[gbase[b] + (j - lscan[b])] = pay[j];
  }
}

// ---------------------------------------------------------------------------
// P4: per-bucket reorder by row in LDS -> final CSR segment + rp (derived:
// segment start in staged == segment start in CSR, so rp[r] = s0 + lscan[rl])
// ---------------------------------------------------------------------------
__global__ __launch_bounds__(256) void p4_emit(
    const int* __restrict__ base, const int2* __restrict__ staged,
    int2* __restrict__ edges, int* __restrict__ rp) {
  __shared__ int h[256], lscan[256], lcur[256];
  __shared__ int tmp[128];
  __shared__ int2 pay[ECAP];
  const int b = blockIdx.x, tid = threadIdx.x;
  const int s0 = base[b * NCH];
  const int s1 = (b == NB2 - 1) ? NE : base[(b + 1) * NCH];
  const int cnt = s1 - s0;
  h[tid] = 0;
  lcur[tid] = 0;
  __syncthreads();
  for (int j = tid; j < cnt; j += 256) atomicAdd(&h[staged[s0 + j].x & 255], 1);
  __syncthreads();
  if (tid < 128) tmp[tid] = h[2 * tid] + h[2 * tid + 1];
  __syncthreads();
  for (int off = 1; off < 128; off <<= 1) {
    int v = (tid < 128 && tid >= off) ? tmp[tid - off] : 0;
    __syncthreads();
    if (tid < 128) tmp[tid] += v;
    __syncthreads();
  }
  if (tid < 128) {
    int a = h[2 * tid];
    int excl = tmp[tid] - (a + h[2 * tid + 1]);
    lscan[2 * tid] = excl;
    lscan[2 * tid + 1] = excl + a;
  }
  __syncthreads();
  if (cnt <= ECAP) {
    for (int j = tid; j < cnt; j += 256) {
      int2 ed = staged[s0 + j];
      int rl = ed.x & 255;
      int p = lscan[rl] + atomicAdd(&lcur[rl], 1);
      pay[p] = make_int2((int)((unsigned)ed.x >> 8), ed.y);
    }
    __syncthreads();
    for (int j = tid; j < cnt; j += 256) edges[s0 + j] = pay[j];
  } else {  // statistically unreachable fallback: direct scatter within segment
    for (int j = tid; j < cnt; j += 256) {
      int2 ed = staged[s0 + j];
      int rl = ed.x & 255;
      int p = lscan[rl] + atomicAdd(&lcur[rl], 1);
      edges[s0 + p] = make_int2((int)((unsigned)ed.x >> 8), ed.y);
    }
  }
  // rp for this bucket's rows (covers rp[NN] at b=510, t=40)
  if (tid < RPB2) {
    int r = b * RPB2 + tid;
    if (r <= NN) rp[r] = s0 + lscan[tid];
  }
}

// ---------------------------------------------------------------------------
// Propagation: x_out = 0.9 * (A x_in) + 0.1 * h.  10 threads per node.
// ---------------------------------------------------------------------------
__global__ __launch_bounds__(256) void prop_kernel(
    const float4* __restrict__ xin, float4* __restrict__ xout,
    const float4* __restrict__ h, const int2* __restrict__ edges,
    const int* __restrict__ rp) {
  const int t = blockIdx.x * 256 + threadIdx.x;
  const int node = t / 10;
  if (node >= NN) return;
  const int g = t - node * 10;
  const int e0 = rp[node], e1 = rp[node + 1];
  float4 acc = make_float4(0.f, 0.f, 0.f, 0.f);
  for (int e = e0; e < e1; ++e) {
    int2 ed = edges[e];
    float v = __int_as_float(ed.y);
    float4 x = xin[(long)ed.x * 10 + g];
    acc.x = fmaf(v, x.x, acc.x);
    acc.y = fmaf(v, x.y, acc.y);
    acc.z = fmaf(v, x.z, acc.z);
    acc.w = fmaf(v, x.w, acc.w);
  }
  float4 hh = h[(long)node * 10 + g];
  float4 o;
  o.x = fmaf(0.9f, acc.x, 0.1f * hh.x);
  o.y = fmaf(0.9f, acc.y, 0.1f * hh.y);
  o.z = fmaf(0.9f, acc.z, 0.1f * hh.z);
  o.w = fmaf(0.9f, acc.w, 0.1f * hh.w);
  xout[(long)node * 10 + g] = o;
}

// ---------------------------------------------------------------------------
// log_softmax over 40 classes, one thread per node
// ---------------------------------------------------------------------------
__global__ __launch_bounds__(256) void logsm_kernel(const float* __restrict__ X,
                                                    float* __restrict__ out) {
  const int node = blockIdx.x * 256 + threadIdx.x;
  if (node >= NN) return;
  const float4* x4 = (const float4*)(X + (long)node * NCLS);
  float v[NCLS];
#pragma unroll
  for (int q = 0; q < 10; ++q) {
    float4 a = x4[q];
    v[q * 4] = a.x; v[q * 4 + 1] = a.y; v[q * 4 + 2] = a.z; v[q * 4 + 3] = a.w;
  }
  float m = v[0];
#pragma unroll
  for (int j = 1; j < NCLS; ++j) m = fmaxf(m, v[j]);
  float s = 0.f;
#pragma unroll
  for (int j = 0; j < NCLS; ++j) s += expf(v[j] - m);
  const float l = m + logf(s);
  float4* o4 = (float4*)(out + (long)node * NCLS);
#pragma unroll
  for (int q = 0; q < 10; ++q) {
    float4 a = make_float4(v[q * 4] - l, v[q * 4 + 1] - l, v[q * 4 + 2] - l,
                           v[q * 4 + 3] - l);
    o4[q] = a;
  }
}

// ---------------------------------------------------------------------------
// Launch
// ---------------------------------------------------------------------------
extern "C" void kernel_launch(void* const* d_in, const int* in_sizes, int n_in,
                              void* d_out, int out_size, void* d_ws,
                              size_t ws_size, hipStream_t stream) {
  const float* F = (const float*)d_in[0];
  const int* EI = (const int*)d_in[1];
  const float* EV = (const float*)d_in[2];
  const float* W1 = (const float*)d_in[3];
  const float* b1 = (const float*)d_in[4];
  const float* W2 = (const float*)d_in[5];
  const float* b2 = (const float*)d_in[6];
  float* out = (float*)d_out;
  char* ws = (char*)d_ws;

  // ws layout, phase-aliased:
  //   build:  STAGED [0,25.6M)  HIST@42M  BASE@43.7M  EDG [48M,73.6M)  RP@73.6M
  //   gemms:  H [16M,41.6M) (STAGED dead)
  //   prop :  X0 [0,16M)  XA [16M,32M)  XB [32M,48M)  EDG, RP
  int2* STAGED = (int2*)(ws + 0);
  float* X0 = (float*)(ws + 0);
  float* XA = (float*)(ws + 16000000);
  float* H = (float*)(ws + 16000000);
  float* XB = (float*)(ws + 32000000);
  int* HIST = (int*)(ws + 42000000);  // NCH*NB2 ints = 1,601,536 B
  int* BASE = (int*)(ws + 43700000);  // NCH*NB2 ints
  int2* EDG = (int2*)(ws + 48000000);
  int* RP = (int*)(ws + 73600000);  // NN+1 ints -> ends 74,000,004

  const int* ROW = EI;       // edge_index[0]
  const int* COL = EI + NE;  // edge_index[1]

  // --- CSR build (4 kernels, no memsets, no global atomics) ---
  p1_count<<<NCH, 256, 0, stream>>>(ROW, HIST);
  p2_scan<<<1, 1024, 0, stream>>>(HIST, BASE);
  p3_scatter<<<NCH, 256, 0, stream>>>(ROW, COL, EV, BASE, STAGED);
  p4_emit<<<NB2, 256, 0, stream>>>(BASE, STAGED, EDG, RP);

  // --- MLP ---
  gemm1_kernel<<<(NN + 63) / 64, 256, 0, stream>>>(F, W1, b1, H);
  gemm2_kernel<<<(NN + 255) / 256, 256, 0, stream>>>(H, W2, b2, X0);

  // --- propagation ---
  const int tgrid = (NN * 10 + 255) / 256;
  const float* cur_in = X0;
  float* bufs[2] = {XA, XB};
  for (int it = 0; it < 10; ++it) {
    float* o = bufs[it & 1];
    prop_kernel<<<tgrid, 256, 0, stream>>>((const float4*)cur_in, (float4*)o,
                                           (const float4*)X0, EDG, RP);
    cur_in = o;
  }
  logsm_kernel<<<(NN + 255) / 256, 256, 0, stream>>>(cur_in, out);
}

// Round 4
// 1542.239 us; speedup vs baseline: 1.3277x; 1.1132x over previous
//
#include <hip/hip_runtime.h>
#include <hip/hip_bf16.h>

// Problem constants (match reference)
#define NN 100000
#define NE 3200000
#define F_IN 512
#define NHID 64
#define NCLS 40

// Radix-partition CSR build params
#define NB2 512   // row buckets
#define RPB2 196  // rows per bucket (512*196 = 100352 >= NN)
#define CHK 4096  // edges per chunk
#define NCH 782   // ceil(NE/CHK)
#define EPT 16    // edges per thread in P3 (CHK/256)
#define ECAP 7168 // emit LDS capacity (mean 6250, sigma 79 -> +11.6 sigma)
#define TOT (NB2 * NCH)  // 400,384 = 391 * 1024 exactly
#define NSB 391   // scan blocks

// ---------------------------------------------------------------------------
// GEMM1: H[N,64] = relu(F[N,512] @ W1[512,64] + b1)
// ---------------------------------------------------------------------------
__global__ __launch_bounds__(256) void gemm1_kernel(
    const float* __restrict__ F, const float* __restrict__ W1,
    const float* __restrict__ b1, float* __restrict__ H) {
  __shared__ float As[16][68];
  __shared__ float Bs[16][64];
  const int tid = threadIdx.x;
  const int m0 = blockIdx.x * 64;
  const int ty = tid >> 4;
  const int tx = tid & 15;
  const int lrowA = tid >> 2;
  const int lkA = (tid & 3) * 4;
  const int lkB = tid >> 4;
  const int lcolB = (tid & 15) * 4;
  const bool rowok = (m0 + lrowA) < NN;
  const int rclamp = rowok ? (m0 + lrowA) : (NN - 1);
  const float* Fb = F + (long)rclamp * F_IN + lkA;

  float acc[4][4] = {};
  for (int k0 = 0; k0 < F_IN; k0 += 16) {
    float4 fa = *(const float4*)(Fb + k0);
    if (!rowok) fa = make_float4(0.f, 0.f, 0.f, 0.f);
    float4 wb = *(const float4*)(W1 + (long)(k0 + lkB) * NHID + lcolB);
    __syncthreads();
    As[lkA + 0][lrowA] = fa.x;
    As[lkA + 1][lrowA] = fa.y;
    As[lkA + 2][lrowA] = fa.z;
    As[lkA + 3][lrowA] = fa.w;
    *(float4*)&Bs[lkB][lcolB] = wb;
    __syncthreads();
#pragma unroll
    for (int kk = 0; kk < 16; ++kk) {
      float4 a = *(const float4*)&As[kk][ty * 4];
      float4 b = *(const float4*)&Bs[kk][tx * 4];
      float av[4] = {a.x, a.y, a.z, a.w};
      float bv[4] = {b.x, b.y, b.z, b.w};
#pragma unroll
      for (int i = 0; i < 4; ++i)
#pragma unroll
        for (int j = 0; j < 4; ++j) acc[i][j] = fmaf(av[i], bv[j], acc[i][j]);
    }
  }
  float4 bb = *(const float4*)(b1 + tx * 4);
  float bv[4] = {bb.x, bb.y, bb.z, bb.w};
#pragma unroll
  for (int i = 0; i < 4; ++i) {
    int r = m0 + ty * 4 + i;
    if (r < NN) {
      float4 o;
      o.x = fmaxf(acc[i][0] + bv[0], 0.f);
      o.y = fmaxf(acc[i][1] + bv[1], 0.f);
      o.z = fmaxf(acc[i][2] + bv[2], 0.f);
      o.w = fmaxf(acc[i][3] + bv[3], 0.f);
      *(float4*)(H + (long)r * NHID + tx * 4) = o;
    }
  }
}

// ---------------------------------------------------------------------------
// GEMM2: X0[N,40] = H[N,64] @ W2[64,40] + b2   (thread per node)
// ---------------------------------------------------------------------------
__global__ __launch_bounds__(256) void gemm2_kernel(
    const float* __restrict__ H, const float* __restrict__ W2,
    const float* __restrict__ b2, float* __restrict__ X0) {
  __shared__ float Ws[NHID * NCLS];
  __shared__ float bs[NCLS];
  const int tid = threadIdx.x;
  for (int i = tid; i < NHID * NCLS; i += 256) Ws[i] = W2[i];
  if (tid < NCLS) bs[tid] = b2[tid];
  __syncthreads();
  const int node = blockIdx.x * 256 + tid;
  if (node >= NN) return;
  float acc[NCLS];
#pragma unroll
  for (int j = 0; j < NCLS; ++j) acc[j] = bs[j];
  const float4* h4 = (const float4*)(H + (long)node * NHID);
#pragma unroll
  for (int kq = 0; kq < 16; ++kq) {
    float4 h = h4[kq];
    float hv[4] = {h.x, h.y, h.z, h.w};
#pragma unroll
    for (int u = 0; u < 4; ++u) {
      const int k = kq * 4 + u;
#pragma unroll
      for (int j = 0; j < NCLS; ++j)
        acc[j] = fmaf(hv[u], Ws[k * NCLS + j], acc[j]);
    }
  }
  float* o = X0 + (long)node * NCLS;
#pragma unroll
  for (int q = 0; q < 10; ++q) {
    float4 v = make_float4(acc[q * 4], acc[q * 4 + 1], acc[q * 4 + 2], acc[q * 4 + 3]);
    *(float4*)(o + q * 4) = v;
  }
}

// ---------------------------------------------------------------------------
// P1: per-chunk bucket histogram (LDS atomics, coalesced dump)
// ---------------------------------------------------------------------------
__global__ __launch_bounds__(256) void p1_count(const int* __restrict__ row,
                                                int* __restrict__ hist) {
  __shared__ int h[NB2];
  const int tid = threadIdx.x, blk = blockIdx.x;
  for (int i = tid; i < NB2; i += 256) h[i] = 0;
  __syncthreads();
  const int e0 = blk * CHK;
#pragma unroll
  for (int k = 0; k < EPT; ++k) {
    int e = e0 + k * 256 + tid;
    if (e < NE) atomicAdd(&h[row[e] / RPB2], 1);
  }
  __syncthreads();
  for (int i = tid; i < NB2; i += 256) hist[blk * NB2 + i] = h[i];
}

// ---------------------------------------------------------------------------
// P2 hierarchical scan over flat order f = b*NCH + blk (reads hist[blk][b]).
// hist is 1.6 MB -> L2-resident; strided reads OK when parallel.
// ---------------------------------------------------------------------------
__global__ __launch_bounds__(1024) void p2a_scan(const int* __restrict__ hist,
                                                 int* __restrict__ base,
                                                 int* __restrict__ bsum) {
  __shared__ int sm[1024];
  const int t = threadIdx.x;
  const int f = blockIdx.x * 1024 + t;  // grid covers TOT exactly
  const int b = f / NCH, blk = f - b * NCH;
  const int v = hist[blk * NB2 + b];
  sm[t] = v;
  __syncthreads();
  for (int off = 1; off < 1024; off <<= 1) {
    int u = (t >= off) ? sm[t - off] : 0;
    __syncthreads();
    sm[t] += u;
    __syncthreads();
  }
  base[f] = sm[t] - v;  // block-local exclusive
  if (t == 1023) bsum[blockIdx.x] = sm[t];
}

__global__ __launch_bounds__(512) void p2b_scan(const int* __restrict__ bsum,
                                                int* __restrict__ boff) {
  __shared__ int sm[512];
  const int t = threadIdx.x;
  const int v = (t < NSB) ? bsum[t] : 0;
  sm[t] = v;
  __syncthreads();
  for (int off = 1; off < 512; off <<= 1) {
    int u = (t >= off) ? sm[t - off] : 0;
    __syncthreads();
    sm[t] += u;
    __syncthreads();
  }
  if (t < NSB) boff[t] = sm[t] - v;
}

__global__ __launch_bounds__(1024) void p2c_add(int* __restrict__ base,
                                                const int* __restrict__ boff) {
  const int f = blockIdx.x * 1024 + threadIdx.x;
  base[f] += boff[blockIdx.x];
}

// ---------------------------------------------------------------------------
// P3: partition into 512 buckets. All reordering in LDS; global writes are
// block-private contiguous runs (single-workgroup line ownership).
// staged.x = (col<<8) | row_local (col<2^17, rl<196);  staged.y = ev bits
// ---------------------------------------------------------------------------
__global__ __launch_bounds__(256) void p3_scatter(
    const int* __restrict__ row, const int* __restrict__ col,
    const float* __restrict__ ev, const int* __restrict__ base,
    int2* __restrict__ staged) {
  __shared__ int h[NB2], lscan[NB2], lcur[NB2], gbase[NB2];
  __shared__ int tmp[256];
  __shared__ int2 pay[CHK];
  __shared__ unsigned short binof[CHK];
  const int tid = threadIdx.x, blk = blockIdx.x;
  for (int i = tid; i < NB2; i += 256) { h[i] = 0; lcur[i] = 0; }
  __syncthreads();
  const int e0 = blk * CHK;
  const int n = (NE - e0 < CHK) ? (NE - e0) : CHK;
  int eb[EPT], em[EPT], ee[EPT];
#pragma unroll
  for (int k = 0; k < EPT; ++k) {
    int e = e0 + k * 256 + tid;
    if (e < NE) {
      int r = row[e];
      int b = r / RPB2;
      eb[k] = b;
      em[k] = (col[e] << 8) | (r - b * RPB2);
      ee[k] = __float_as_int(ev[e]);
      atomicAdd(&h[b], 1);
    } else {
      eb[k] = -1;
    }
  }
  __syncthreads();
  int a = h[2 * tid], c = h[2 * tid + 1];
  tmp[tid] = a + c;
  __syncthreads();
  for (int off = 1; off < 256; off <<= 1) {
    int v = (tid >= off) ? tmp[tid - off] : 0;
    __syncthreads();
    tmp[tid] += v;
    __syncthreads();
  }
  int excl = tmp[tid] - (a + c);
  lscan[2 * tid] = excl;
  lscan[2 * tid + 1] = excl + a;
  gbase[2 * tid] = base[(2 * tid) * NCH + blk];
  gbase[2 * tid + 1] = base[(2 * tid + 1) * NCH + blk];
  __syncthreads();
#pragma unroll
  for (int k = 0; k < EPT; ++k) {
    if (eb[k] >= 0) {
      int b = eb[k];
      int p = lscan[b] + atomicAdd(&lcur[b], 1);
      pay[p] = make_int2(em[k], ee[k]);
      binof[p] = (unsigned short)b;
    }
  }
  __syncthreads();
  for (int j = tid; j < n; j += 256) {
    int b = binof[j];
    staged[gbase[b] + (j - lscan[b])] = pay[j];
  }
}

// ---------------------------------------------------------------------------
// P4: per-bucket reorder by row in LDS -> final CSR segment + rp (derived)
// ---------------------------------------------------------------------------
__global__ __launch_bounds__(256) void p4_emit(
    const int* __restrict__ base, const int2* __restrict__ staged,
    int2* __restrict__ edges, int* __restrict__ rp) {
  __shared__ int h[256], lscan[256], lcur[256];
  __shared__ int tmp[128];
  __shared__ int2 pay[ECAP];
  const int b = blockIdx.x, tid = threadIdx.x;
  const int s0 = base[b * NCH];
  const int s1 = (b == NB2 - 1) ? NE : base[(b + 1) * NCH];
  const int cnt = s1 - s0;
  h[tid] = 0;
  lcur[tid] = 0;
  __syncthreads();
  for (int j = tid; j < cnt; j += 256) atomicAdd(&h[staged[s0 + j].x & 255], 1);
  __syncthreads();
  if (tid < 128) tmp[tid] = h[2 * tid] + h[2 * tid + 1];
  __syncthreads();
  for (int off = 1; off < 128; off <<= 1) {
    int v = (tid < 128 && tid >= off) ? tmp[tid - off] : 0;
    __syncthreads();
    if (tid < 128) tmp[tid] += v;
    __syncthreads();
  }
  if (tid < 128) {
    int a = h[2 * tid];
    int excl = tmp[tid] - (a + h[2 * tid + 1]);
    lscan[2 * tid] = excl;
    lscan[2 * tid + 1] = excl + a;
  }
  __syncthreads();
  if (cnt <= ECAP) {
    for (int j = tid; j < cnt; j += 256) {
      int2 ed = staged[s0 + j];
      int rl = ed.x & 255;
      int p = lscan[rl] + atomicAdd(&lcur[rl], 1);
      pay[p] = make_int2((int)((unsigned)ed.x >> 8), ed.y);
    }
    __syncthreads();
    for (int j = tid; j < cnt; j += 256) edges[s0 + j] = pay[j];
  } else {
    for (int j = tid; j < cnt; j += 256) {
      int2 ed = staged[s0 + j];
      int rl = ed.x & 255;
      int p = lscan[rl] + atomicAdd(&lcur[rl], 1);
      edges[s0 + p] = make_int2((int)((unsigned)ed.x >> 8), ed.y);
    }
  }
  if (tid < RPB2) {
    int r = b * RPB2 + tid;
    if (r <= NN) rp[r] = s0 + lscan[tid];
  }
}

// ---------------------------------------------------------------------------
// Propagation: x_out = 0.9 * (A x_in) + 0.1 * h.  10 threads per node.
// ---------------------------------------------------------------------------
__global__ __launch_bounds__(256) void prop_kernel(
    const float4* __restrict__ xin, float4* __restrict__ xout,
    const float4* __restrict__ h, const int2* __restrict__ edges,
    const int* __restrict__ rp) {
  const int t = blockIdx.x * 256 + threadIdx.x;
  const int node = t / 10;
  if (node >= NN) return;
  const int g = t - node * 10;
  const int e0 = rp[node], e1 = rp[node + 1];
  float4 acc = make_float4(0.f, 0.f, 0.f, 0.f);
  for (int e = e0; e < e1; ++e) {
    int2 ed = edges[e];
    float v = __int_as_float(ed.y);
    float4 x = xin[(long)ed.x * 10 + g];
    acc.x = fmaf(v, x.x, acc.x);
    acc.y = fmaf(v, x.y, acc.y);
    acc.z = fmaf(v, x.z, acc.z);
    acc.w = fmaf(v, x.w, acc.w);
  }
  float4 hh = h[(long)node * 10 + g];
  float4 o;
  o.x = fmaf(0.9f, acc.x, 0.1f * hh.x);
  o.y = fmaf(0.9f, acc.y, 0.1f * hh.y);
  o.z = fmaf(0.9f, acc.z, 0.1f * hh.z);
  o.w = fmaf(0.9f, acc.w, 0.1f * hh.w);
  xout[(long)node * 10 + g] = o;
}

// ---------------------------------------------------------------------------
// log_softmax over 40 classes, one thread per node
// ---------------------------------------------------------------------------
__global__ __launch_bounds__(256) void logsm_kernel(const float* __restrict__ X,
                                                    float* __restrict__ out) {
  const int node = blockIdx.x * 256 + threadIdx.x;
  if (node >= NN) return;
  const float4* x4 = (const float4*)(X + (long)node * NCLS);
  float v[NCLS];
#pragma unroll
  for (int q = 0; q < 10; ++q) {
    float4 a = x4[q];
    v[q * 4] = a.x; v[q * 4 + 1] = a.y; v[q * 4 + 2] = a.z; v[q * 4 + 3] = a.w;
  }
  float m = v[0];
#pragma unroll
  for (int j = 1; j < NCLS; ++j) m = fmaxf(m, v[j]);
  float s = 0.f;
#pragma unroll
  for (int j = 0; j < NCLS; ++j) s += expf(v[j] - m);
  const float l = m + logf(s);
  float4* o4 = (float4*)(out + (long)node * NCLS);
#pragma unroll
  for (int q = 0; q < 10; ++q) {
    float4 a = make_float4(v[q * 4] - l, v[q * 4 + 1] - l, v[q * 4 + 2] - l,
                           v[q * 4 + 3] - l);
    o4[q] = a;
  }
}

// ---------------------------------------------------------------------------
// Launch
// ---------------------------------------------------------------------------
extern "C" void kernel_launch(void* const* d_in, const int* in_sizes, int n_in,
                              void* d_out, int out_size, void* d_ws,
                              size_t ws_size, hipStream_t stream) {
  const float* F = (const float*)d_in[0];
  const int* EI = (const int*)d_in[1];
  const float* EV = (const float*)d_in[2];
  const float* W1 = (const float*)d_in[3];
  const float* b1 = (const float*)d_in[4];
  const float* W2 = (const float*)d_in[5];
  const float* b2 = (const float*)d_in[6];
  float* out = (float*)d_out;
  char* ws = (char*)d_ws;

  // ws layout, phase-aliased:
  //   build:  STAGED [0,25.6M)  HIST@42M  BASE@43.7M  BSUM/BOFF@45.4M
  //           EDG [48M,73.6M)  RP@73.6M
  //   gemms:  H [16M,41.6M) (STAGED dead)
  //   prop :  X0 [0,16M)  XA [16M,32M)  XB [32M,48M)  EDG, RP
  int2* STAGED = (int2*)(ws + 0);
  float* X0 = (float*)(ws + 0);
  float* XA = (float*)(ws + 16000000);
  float* H = (float*)(ws + 16000000);
  float* XB = (float*)(ws + 32000000);
  int* HIST = (int*)(ws + 42000000);  // TOT ints = 1,601,536 B
  int* BASE = (int*)(ws + 43700000);  // TOT ints
  int* BSUM = (int*)(ws + 45400000);  // NSB ints
  int* BOFF = (int*)(ws + 45402048);  // NSB ints
  int2* EDG = (int2*)(ws + 48000000);
  int* RP = (int*)(ws + 73600000);  // NN+1 ints -> ends 74,000,004

  const int* ROW = EI;       // edge_index[0]
  const int* COL = EI + NE;  // edge_index[1]

  // --- CSR build (no memsets, no global atomics) ---
  p1_count<<<NCH, 256, 0, stream>>>(ROW, HIST);
  p2a_scan<<<NSB, 1024, 0, stream>>>(HIST, BASE, BSUM);
  p2b_scan<<<1, 512, 0, stream>>>(BSUM, BOFF);
  p2c_add<<<NSB, 1024, 0, stream>>>(BASE, BOFF);
  p3_scatter<<<NCH, 256, 0, stream>>>(ROW, COL, EV, BASE, STAGED);
  p4_emit<<<NB2, 256, 0, stream>>>(BASE, STAGED, EDG, RP);

  // --- MLP ---
  gemm1_kernel<<<(NN + 63) / 64, 256, 0, stream>>>(F, W1, b1, H);
  gemm2_kernel<<<(NN + 255) / 256, 256, 0, stream>>>(H, W2, b2, X0);

  // --- propagation ---
  const int tgrid = (NN * 10 + 255) / 256;
  const float* cur_in = X0;
  float* bufs[2] = {XA, XB};
  for (int it = 0; it < 10; ++it) {
    float* o = bufs[it & 1];
    prop_kernel<<<tgrid, 256, 0, stream>>>((const float4*)cur_in, (float4*)o,
                                           (const float4*)X0, EDG, RP);
    cur_in = o;
  }
  logsm_kernel<<<(NN + 255) / 256, 256, 0, stream>>>(cur_in, out);
}

// Round 5
// 1232.394 us; speedup vs baseline: 1.6615x; 1.2514x over previous
//
#include <hip/hip_runtime.h>
#include <hip/hip_bf16.h>

// Problem constants (match reference)
#define NN 100000
#define NE 3200000
#define F_IN 512
#define NHID 64
#define NCLS 40

// Radix-partition CSR build params
#define NB2 512   // row buckets
#define RPB2 196  // rows per bucket (512*196 = 100352 >= NN)
#define CHK 4096  // edges per chunk
#define NCH 782   // ceil(NE/CHK)
#define EPT 16    // edges per thread in P3 (CHK/256)
#define ECAP 7168 // emit LDS capacity (mean 6250, sigma 79 -> +11.6 sigma)
#define TOT (NB2 * NCH)  // 400,384 = 391 * 1024 exactly
#define NSB 391   // scan blocks

// bf16 helpers (exact up-convert; RNE down-convert)
__device__ __forceinline__ float bf2f(unsigned short u) {
  return __uint_as_float((unsigned)u << 16);
}
__device__ __forceinline__ unsigned short f2bf(float f) {
  unsigned u = __float_as_uint(f);
  u += 0x7FFFu + ((u >> 16) & 1u);  // round-to-nearest-even
  return (unsigned short)(u >> 16);
}

// ---------------------------------------------------------------------------
// GEMM1: H[N,64] = relu(F[N,512] @ W1[512,64] + b1)
// ---------------------------------------------------------------------------
__global__ __launch_bounds__(256) void gemm1_kernel(
    const float* __restrict__ F, const float* __restrict__ W1,
    const float* __restrict__ b1, float* __restrict__ H) {
  __shared__ float As[16][68];
  __shared__ float Bs[16][64];
  const int tid = threadIdx.x;
  const int m0 = blockIdx.x * 64;
  const int ty = tid >> 4;
  const int tx = tid & 15;
  const int lrowA = tid >> 2;
  const int lkA = (tid & 3) * 4;
  const int lkB = tid >> 4;
  const int lcolB = (tid & 15) * 4;
  const bool rowok = (m0 + lrowA) < NN;
  const int rclamp = rowok ? (m0 + lrowA) : (NN - 1);
  const float* Fb = F + (long)rclamp * F_IN + lkA;

  float acc[4][4] = {};
  for (int k0 = 0; k0 < F_IN; k0 += 16) {
    float4 fa = *(const float4*)(Fb + k0);
    if (!rowok) fa = make_float4(0.f, 0.f, 0.f, 0.f);
    float4 wb = *(const float4*)(W1 + (long)(k0 + lkB) * NHID + lcolB);
    __syncthreads();
    As[lkA + 0][lrowA] = fa.x;
    As[lkA + 1][lrowA] = fa.y;
    As[lkA + 2][lrowA] = fa.z;
    As[lkA + 3][lrowA] = fa.w;
    *(float4*)&Bs[lkB][lcolB] = wb;
    __syncthreads();
#pragma unroll
    for (int kk = 0; kk < 16; ++kk) {
      float4 a = *(const float4*)&As[kk][ty * 4];
      float4 b = *(const float4*)&Bs[kk][tx * 4];
      float av[4] = {a.x, a.y, a.z, a.w};
      float bv[4] = {b.x, b.y, b.z, b.w};
#pragma unroll
      for (int i = 0; i < 4; ++i)
#pragma unroll
        for (int j = 0; j < 4; ++j) acc[i][j] = fmaf(av[i], bv[j], acc[i][j]);
    }
  }
  float4 bb = *(const float4*)(b1 + tx * 4);
  float bv[4] = {bb.x, bb.y, bb.z, bb.w};
#pragma unroll
  for (int i = 0; i < 4; ++i) {
    int r = m0 + ty * 4 + i;
    if (r < NN) {
      float4 o;
      o.x = fmaxf(acc[i][0] + bv[0], 0.f);
      o.y = fmaxf(acc[i][1] + bv[1], 0.f);
      o.z = fmaxf(acc[i][2] + bv[2], 0.f);
      o.w = fmaxf(acc[i][3] + bv[3], 0.f);
      *(float4*)(H + (long)r * NHID + tx * 4) = o;
    }
  }
}

// ---------------------------------------------------------------------------
// GEMM2: X0 = H @ W2 + b2. Writes fp32 X0 (residual h) AND bf16 X0b (prop).
// ---------------------------------------------------------------------------
__global__ __launch_bounds__(256) void gemm2_kernel(
    const float* __restrict__ H, const float* __restrict__ W2,
    const float* __restrict__ b2, float* __restrict__ X0,
    ushort4* __restrict__ X0b) {
  __shared__ float Ws[NHID * NCLS];
  __shared__ float bs[NCLS];
  const int tid = threadIdx.x;
  for (int i = tid; i < NHID * NCLS; i += 256) Ws[i] = W2[i];
  if (tid < NCLS) bs[tid] = b2[tid];
  __syncthreads();
  const int node = blockIdx.x * 256 + tid;
  if (node >= NN) return;
  float acc[NCLS];
#pragma unroll
  for (int j = 0; j < NCLS; ++j) acc[j] = bs[j];
  const float4* h4 = (const float4*)(H + (long)node * NHID);
#pragma unroll
  for (int kq = 0; kq < 16; ++kq) {
    float4 h = h4[kq];
    float hv[4] = {h.x, h.y, h.z, h.w};
#pragma unroll
    for (int u = 0; u < 4; ++u) {
      const int k = kq * 4 + u;
#pragma unroll
      for (int j = 0; j < NCLS; ++j)
        acc[j] = fmaf(hv[u], Ws[k * NCLS + j], acc[j]);
    }
  }
  float* o = X0 + (long)node * NCLS;
#pragma unroll
  for (int q = 0; q < 10; ++q) {
    *(float4*)(o + q * 4) = make_float4(acc[q * 4], acc[q * 4 + 1],
                                        acc[q * 4 + 2], acc[q * 4 + 3]);
    X0b[node * 10 + q] = make_ushort4(f2bf(acc[q * 4]), f2bf(acc[q * 4 + 1]),
                                      f2bf(acc[q * 4 + 2]), f2bf(acc[q * 4 + 3]));
  }
}

// ---------------------------------------------------------------------------
// P1: per-chunk bucket histogram (LDS atomics, coalesced dump)
// ---------------------------------------------------------------------------
__global__ __launch_bounds__(256) void p1_count(const int* __restrict__ row,
                                                int* __restrict__ hist) {
  __shared__ int h[NB2];
  const int tid = threadIdx.x, blk = blockIdx.x;
  for (int i = tid; i < NB2; i += 256) h[i] = 0;
  __syncthreads();
  const int e0 = blk * CHK;
#pragma unroll
  for (int k = 0; k < EPT; ++k) {
    int e = e0 + k * 256 + tid;
    if (e < NE) atomicAdd(&h[row[e] / RPB2], 1);
  }
  __syncthreads();
  for (int i = tid; i < NB2; i += 256) hist[blk * NB2 + i] = h[i];
}

// ---------------------------------------------------------------------------
// P2 hierarchical scan over flat order f = b*NCH + blk (reads hist[blk][b]).
// ---------------------------------------------------------------------------
__global__ __launch_bounds__(1024) void p2a_scan(const int* __restrict__ hist,
                                                 int* __restrict__ base,
                                                 int* __restrict__ bsum) {
  __shared__ int sm[1024];
  const int t = threadIdx.x;
  const int f = blockIdx.x * 1024 + t;
  const int b = f / NCH, blk = f - b * NCH;
  const int v = hist[blk * NB2 + b];
  sm[t] = v;
  __syncthreads();
  for (int off = 1; off < 1024; off <<= 1) {
    int u = (t >= off) ? sm[t - off] : 0;
    __syncthreads();
    sm[t] += u;
    __syncthreads();
  }
  base[f] = sm[t] - v;
  if (t == 1023) bsum[blockIdx.x] = sm[t];
}

__global__ __launch_bounds__(512) void p2b_scan(const int* __restrict__ bsum,
                                                int* __restrict__ boff) {
  __shared__ int sm[512];
  const int t = threadIdx.x;
  const int v = (t < NSB) ? bsum[t] : 0;
  sm[t] = v;
  __syncthreads();
  for (int off = 1; off < 512; off <<= 1) {
    int u = (t >= off) ? sm[t - off] : 0;
    __syncthreads();
    sm[t] += u;
    __syncthreads();
  }
  if (t < NSB) boff[t] = sm[t] - v;
}

__global__ __launch_bounds__(1024) void p2c_add(int* __restrict__ base,
                                                const int* __restrict__ boff) {
  const int f = blockIdx.x * 1024 + threadIdx.x;
  base[f] += boff[blockIdx.x];
}

// ---------------------------------------------------------------------------
// P3: partition into 512 buckets; block-private contiguous global writes.
// staged.x = (col<<8) | row_local;  staged.y = ev bits
// ---------------------------------------------------------------------------
__global__ __launch_bounds__(256) void p3_scatter(
    const int* __restrict__ row, const int* __restrict__ col,
    const float* __restrict__ ev, const int* __restrict__ base,
    int2* __restrict__ staged) {
  __shared__ int h[NB2], lscan[NB2], lcur[NB2], gbase[NB2];
  __shared__ int tmp[256];
  __shared__ int2 pay[CHK];
  __shared__ unsigned short binof[CHK];
  const int tid = threadIdx.x, blk = blockIdx.x;
  for (int i = tid; i < NB2; i += 256) { h[i] = 0; lcur[i] = 0; }
  __syncthreads();
  const int e0 = blk * CHK;
  const int n = (NE - e0 < CHK) ? (NE - e0) : CHK;
  int eb[EPT], em[EPT], ee[EPT];
#pragma unroll
  for (int k = 0; k < EPT; ++k) {
    int e = e0 + k * 256 + tid;
    if (e < NE) {
      int r = row[e];
      int b = r / RPB2;
      eb[k] = b;
      em[k] = (col[e] << 8) | (r - b * RPB2);
      ee[k] = __float_as_int(ev[e]);
      atomicAdd(&h[b], 1);
    } else {
      eb[k] = -1;
    }
  }
  __syncthreads();
  int a = h[2 * tid], c = h[2 * tid + 1];
  tmp[tid] = a + c;
  __syncthreads();
  for (int off = 1; off < 256; off <<= 1) {
    int v = (tid >= off) ? tmp[tid - off] : 0;
    __syncthreads();
    tmp[tid] += v;
    __syncthreads();
  }
  int excl = tmp[tid] - (a + c);
  lscan[2 * tid] = excl;
  lscan[2 * tid + 1] = excl + a;
  gbase[2 * tid] = base[(2 * tid) * NCH + blk];
  gbase[2 * tid + 1] = base[(2 * tid + 1) * NCH + blk];
  __syncthreads();
#pragma unroll
  for (int k = 0; k < EPT; ++k) {
    if (eb[k] >= 0) {
      int b = eb[k];
      int p = lscan[b] + atomicAdd(&lcur[b], 1);
      pay[p] = make_int2(em[k], ee[k]);
      binof[p] = (unsigned short)b;
    }
  }
  __syncthreads();
  for (int j = tid; j < n; j += 256) {
    int b = binof[j];
    staged[gbase[b] + (j - lscan[b])] = pay[j];
  }
}

// ---------------------------------------------------------------------------
// P4: per-bucket reorder by row in LDS -> final CSR segment + rp (derived)
// ---------------------------------------------------------------------------
__global__ __launch_bounds__(256) void p4_emit(
    const int* __restrict__ base, const int2* __restrict__ staged,
    int2* __restrict__ edges, int* __restrict__ rp) {
  __shared__ int h[256], lscan[256], lcur[256];
  __shared__ int tmp[128];
  __shared__ int2 pay[ECAP];
  const int b = blockIdx.x, tid = threadIdx.x;
  const int s0 = base[b * NCH];
  const int s1 = (b == NB2 - 1) ? NE : base[(b + 1) * NCH];
  const int cnt = s1 - s0;
  h[tid] = 0;
  lcur[tid] = 0;
  __syncthreads();
  for (int j = tid; j < cnt; j += 256) atomicAdd(&h[staged[s0 + j].x & 255], 1);
  __syncthreads();
  if (tid < 128) tmp[tid] = h[2 * tid] + h[2 * tid + 1];
  __syncthreads();
  for (int off = 1; off < 128; off <<= 1) {
    int v = (tid < 128 && tid >= off) ? tmp[tid - off] : 0;
    __syncthreads();
    if (tid < 128) tmp[tid] += v;
    __syncthreads();
  }
  if (tid < 128) {
    int a = h[2 * tid];
    int excl = tmp[tid] - (a + h[2 * tid + 1]);
    lscan[2 * tid] = excl;
    lscan[2 * tid + 1] = excl + a;
  }
  __syncthreads();
  if (cnt <= ECAP) {
    for (int j = tid; j < cnt; j += 256) {
      int2 ed = staged[s0 + j];
      int rl = ed.x & 255;
      int p = lscan[rl] + atomicAdd(&lcur[rl], 1);
      pay[p] = make_int2((int)((unsigned)ed.x >> 8), ed.y);
    }
    __syncthreads();
    for (int j = tid; j < cnt; j += 256) edges[s0 + j] = pay[j];
  } else {
    for (int j = tid; j < cnt; j += 256) {
      int2 ed = staged[s0 + j];
      int rl = ed.x & 255;
      int p = lscan[rl] + atomicAdd(&lcur[rl], 1);
      edges[s0 + p] = make_int2((int)((unsigned)ed.x >> 8), ed.y);
    }
  }
  if (tid < RPB2) {
    int r = b * RPB2 + tid;
    if (r <= NN) rp[r] = s0 + lscan[tid];
  }
}

// ---------------------------------------------------------------------------
// Propagation (bf16 x): x_out = 0.9*(A x_in) + 0.1*h.  10 threads/node,
// each owns 4 classes (8 B bf16 load per edge; fp32 accumulate).
// ---------------------------------------------------------------------------
__global__ __launch_bounds__(256) void prop_kernel_bf16(
    const ushort4* __restrict__ xin, ushort4* __restrict__ xout,
    const float4* __restrict__ h, const int2* __restrict__ edges,
    const int* __restrict__ rp) {
  const int t = blockIdx.x * 256 + threadIdx.x;
  const int node = t / 10;
  if (node >= NN) return;
  const int g = t - node * 10;
  const int e0 = rp[node], e1 = rp[node + 1];
  float ax = 0.f, ay = 0.f, az = 0.f, aw = 0.f;
  for (int e = e0; e < e1; ++e) {
    int2 ed = edges[e];
    float v = __int_as_float(ed.y);
    ushort4 xb = xin[ed.x * 10 + g];
    ax = fmaf(v, bf2f(xb.x), ax);
    ay = fmaf(v, bf2f(xb.y), ay);
    az = fmaf(v, bf2f(xb.z), az);
    aw = fmaf(v, bf2f(xb.w), aw);
  }
  float4 hh = h[node * 10 + g];
  float ox = fmaf(0.9f, ax, 0.1f * hh.x);
  float oy = fmaf(0.9f, ay, 0.1f * hh.y);
  float oz = fmaf(0.9f, az, 0.1f * hh.z);
  float ow = fmaf(0.9f, aw, 0.1f * hh.w);
  xout[node * 10 + g] = make_ushort4(f2bf(ox), f2bf(oy), f2bf(oz), f2bf(ow));
}

// ---------------------------------------------------------------------------
// log_softmax over 40 classes (bf16 in, fp32 out), one thread per node
// ---------------------------------------------------------------------------
__global__ __launch_bounds__(256) void logsm_kernel(
    const ushort4* __restrict__ X, float* __restrict__ out) {
  const int node = blockIdx.x * 256 + threadIdx.x;
  if (node >= NN) return;
  float v[NCLS];
#pragma unroll
  for (int q = 0; q < 10; ++q) {
    ushort4 a = X[node * 10 + q];
    v[q * 4] = bf2f(a.x);
    v[q * 4 + 1] = bf2f(a.y);
    v[q * 4 + 2] = bf2f(a.z);
    v[q * 4 + 3] = bf2f(a.w);
  }
  float m = v[0];
#pragma unroll
  for (int j = 1; j < NCLS; ++j) m = fmaxf(m, v[j]);
  float s = 0.f;
#pragma unroll
  for (int j = 0; j < NCLS; ++j) s += expf(v[j] - m);
  const float l = m + logf(s);
  float4* o4 = (float4*)(out + (long)node * NCLS);
#pragma unroll
  for (int q = 0; q < 10; ++q)
    o4[q] = make_float4(v[q * 4] - l, v[q * 4 + 1] - l, v[q * 4 + 2] - l,
                        v[q * 4 + 3] - l);
}

// ---------------------------------------------------------------------------
// Launch
// ---------------------------------------------------------------------------
extern "C" void kernel_launch(void* const* d_in, const int* in_sizes, int n_in,
                              void* d_out, int out_size, void* d_ws,
                              size_t ws_size, hipStream_t stream) {
  const float* F = (const float*)d_in[0];
  const int* EI = (const int*)d_in[1];
  const float* EV = (const float*)d_in[2];
  const float* W1 = (const float*)d_in[3];
  const float* b1 = (const float*)d_in[4];
  const float* W2 = (const float*)d_in[5];
  const float* b2 = (const float*)d_in[6];
  float* out = (float*)d_out;
  char* ws = (char*)d_ws;

  // ws layout, phase-aliased:
  //   build:  STAGED [0,25.6M)  HIST@42M  BASE@43.7M  BSUM/BOFF@45.4M
  //           EDG [48M,73.6M)  RP@73.6M
  //   gemms:  H [16M,41.6M)  X0 [0,16M)  X0b@76M (bf16)
  //   prop :  X0 (=h, fp32)  X0b/XAb/XBb bf16 @76/84/92M  EDG, RP
  int2* STAGED = (int2*)(ws + 0);
  float* X0 = (float*)(ws + 0);
  float* H = (float*)(ws + 16000000);
  int* HIST = (int*)(ws + 42000000);
  int* BASE = (int*)(ws + 43700000);
  int* BSUM = (int*)(ws + 45400000);
  int* BOFF = (int*)(ws + 45402048);
  int2* EDG = (int2*)(ws + 48000000);
  int* RP = (int*)(ws + 73600000);
  ushort4* X0b = (ushort4*)(ws + 76000000);  // NN*40 bf16 = 8 MB
  ushort4* XAb = (ushort4*)(ws + 84000000);
  ushort4* XBb = (ushort4*)(ws + 92000000);  // ends at 100 MB

  const int* ROW = EI;       // edge_index[0]
  const int* COL = EI + NE;  // edge_index[1]

  // --- CSR build ---
  p1_count<<<NCH, 256, 0, stream>>>(ROW, HIST);
  p2a_scan<<<NSB, 1024, 0, stream>>>(HIST, BASE, BSUM);
  p2b_scan<<<1, 512, 0, stream>>>(BSUM, BOFF);
  p2c_add<<<NSB, 1024, 0, stream>>>(BASE, BOFF);
  p3_scatter<<<NCH, 256, 0, stream>>>(ROW, COL, EV, BASE, STAGED);
  p4_emit<<<NB2, 256, 0, stream>>>(BASE, STAGED, EDG, RP);

  // --- MLP ---
  gemm1_kernel<<<(NN + 63) / 64, 256, 0, stream>>>(F, W1, b1, H);
  gemm2_kernel<<<(NN + 255) / 256, 256, 0, stream>>>(H, W2, b2, X0, X0b);

  // --- propagation (bf16 x, fp32 h) ---
  const int tgrid = (NN * 10 + 255) / 256;
  const ushort4* cur_in = X0b;
  ushort4* bufs[2] = {XAb, XBb};
  for (int it = 0; it < 10; ++it) {
    ushort4* o = bufs[it & 1];
    prop_kernel_bf16<<<tgrid, 256, 0, stream>>>(cur_in, o, (const float4*)X0,
                                                EDG, RP);
    cur_in = o;
  }
  logsm_kernel<<<(NN + 255) / 256, 256, 0, stream>>>(cur_in, out);
}